// Round 5
// baseline (4983.386 us; speedup 1.0000x reference)
//
#include <hip/hip_runtime.h>
#include <math.h>

#define Bsz 512
#define Fsz 64
#define Hsz 256
#define TSTEPS 128
#define G3 768

#define NBLK 32          // each block owns 16 batch rows, FULL hidden state
#define NTHR 512         // 8 waves; wave w owns h-cols [w*32, w*32+32)
#define SH 264           // padded LDS row stride in shorts (528B = 33*16 -> 2-way banks)
#define PLANE (16*SH)    // shorts per plane

typedef float f32x4 __attribute__((ext_vector_type(4)));
typedef short s16x8 __attribute__((ext_vector_type(8)));

#define MF(a,b,c) __builtin_amdgcn_mfma_f32_16x16x32_bf16(a,b,c,0,0,0)

static __device__ __forceinline__ unsigned short bf16_rne(float f){
    union { float f; unsigned u; } v; v.f = f;
    return (unsigned short)((v.u + 0x7FFFu + ((v.u >> 16) & 1u)) >> 16);
}
static __device__ __forceinline__ float bf16_to_f(unsigned short h){
    union { unsigned u; float f; } v; v.u = ((unsigned)h) << 16; return v.f;
}
static __device__ __forceinline__ void split8(const float* p, s16x8& hi, s16x8& lo){
    #pragma unroll
    for (int t = 0; t < 8; ++t){
        float f = p[t];
        unsigned short h = bf16_rne(f);
        hi[t] = (short)h;
        lo[t] = (short)bf16_rne(f - bf16_to_f(h));
    }
}
// fast transcendentals: v_exp_f32 (2^x) + v_rcp_f32; verified vs absmax in R4
static __device__ __forceinline__ float sigmoidf_(float v){
    return __builtin_amdgcn_rcpf(1.0f + __builtin_amdgcn_exp2f(-1.44269504f*v));
}
static __device__ __forceinline__ float tanhf_(float v){
    return 1.0f - 2.0f*__builtin_amdgcn_rcpf(1.0f + __builtin_amdgcn_exp2f(2.88539008f*v));
}

// ---------------- setup: M = dec_Wih@reg_W, cfold = dec_Wih@reg_b + dec_bih,
// ---------------- gi0 = x[:,127,:]@dec_Wih.T + dec_bih
extern "C" __global__ void gru_setup(const float* __restrict__ x,
                                     const float* __restrict__ dWih,
                                     const float* __restrict__ dbih,
                                     const float* __restrict__ regW,
                                     const float* __restrict__ regb,
                                     float* __restrict__ Mw,
                                     float* __restrict__ cfold,
                                     float* __restrict__ gi0)
{
    int idx = blockIdx.x*blockDim.x + threadIdx.x;
    if (idx < G3*Hsz) {
        int g = idx >> 8, j = idx & 255;
        float a = 0.f;
        #pragma unroll 8
        for (int f = 0; f < Fsz; ++f) a += dWih[g*Fsz + f]*regW[f*Hsz + j];
        Mw[idx] = a;
    } else if (idx < G3*Hsz + G3) {
        int g = idx - G3*Hsz;
        float a = dbih[g];
        #pragma unroll 8
        for (int f = 0; f < Fsz; ++f) a += dWih[g*Fsz + f]*regb[f];
        cfold[g] = a;
    } else {
        int e = idx - (G3*Hsz + G3);
        if (e < Bsz*G3) {
            int b = e / G3, g = e - b*G3;
            const float* xp = x + (size_t)b*(256*64) + 127*64;
            float a = dbih[g];
            #pragma unroll 8
            for (int f = 0; f < Fsz; ++f) a += xp[f]*dWih[g*Fsz + f];
            gi0[e] = a;
        }
    }
}

// ---------------- pack: pre-split weights into MFMA B-fragment streams ----------------
// frag layout: s16x8 entry index = unit*128 + part*64 + lane; lane l supplies
// B[n = nt*16 + (l&15)][k = kt*32 + (l>>4)*8 + 0..8), part 0 = bf16-hi, 1 = lo.
// units: fEWhh: u=ct*24+g*8+kt (384); fEWih: ct*6+g*2+kt (96);
//        fRZc (dWhh+Mw, gates r,z): ct*16+g*8+kt (256); fRZp (pure dWhh r,z): 256;
//        fWn (dWhh n): ct*8+kt (128); fMn (Mw n): 128; fRW (regW): nt*8+kt (32).
extern "C" __global__ void gru_pack(const float* __restrict__ eWhh,
                                    const float* __restrict__ eWih,
                                    const float* __restrict__ dWhh,
                                    const float* __restrict__ Mw,
                                    const float* __restrict__ regW,
                                    s16x8* __restrict__ fEWhh, s16x8* __restrict__ fEWih,
                                    s16x8* __restrict__ fRZc,  s16x8* __restrict__ fRZp,
                                    s16x8* __restrict__ fWn,   s16x8* __restrict__ fMn,
                                    s16x8* __restrict__ fRW)
{
    const int u = blockIdx.x;
    const int l = threadIdx.x;           // 64
    const int r = l & 15, q = l >> 4;
    float v[8];
    s16x8* dst;
    if (u < 384){                                    // enc Whh
        int ct = u/24, g = (u/8)%3, kt = u&7;
        const float* s = eWhh + (size_t)(g*256 + ct*16 + r)*256 + kt*32 + q*8;
        #pragma unroll
        for (int e = 0; e < 8; ++e) v[e] = s[e];
        dst = fEWhh + (size_t)u*128;
    } else if (u < 480){                             // enc Wih
        int u2 = u-384; int ct = u2/6, g = (u2/2)%3, kt = u2&1;
        const float* s = eWih + (size_t)(g*256 + ct*16 + r)*64 + kt*32 + q*8;
        #pragma unroll
        for (int e = 0; e < 8; ++e) v[e] = s[e];
        dst = fEWih + (size_t)u2*128;
    } else if (u < 736){                             // dec RZ combined (Whh+M)
        int u2 = u-480; int ct = u2/16, g = (u2/8)%2, kt = u2&7;
        size_t o = (size_t)(g*256 + ct*16 + r)*256 + kt*32 + q*8;
        #pragma unroll
        for (int e = 0; e < 8; ++e) v[e] = dWhh[o+e] + Mw[o+e];
        dst = fRZc + (size_t)u2*128;
    } else if (u < 992){                             // dec RZ pure Whh (step-0)
        int u2 = u-736; int ct = u2/16, g = (u2/8)%2, kt = u2&7;
        const float* s = dWhh + (size_t)(g*256 + ct*16 + r)*256 + kt*32 + q*8;
        #pragma unroll
        for (int e = 0; e < 8; ++e) v[e] = s[e];
        dst = fRZp + (size_t)u2*128;
    } else if (u < 1120){                            // dec Whh n-gate
        int u2 = u-992; int ct = u2/8, kt = u2&7;
        const float* s = dWhh + (size_t)(512 + ct*16 + r)*256 + kt*32 + q*8;
        #pragma unroll
        for (int e = 0; e < 8; ++e) v[e] = s[e];
        dst = fWn + (size_t)u2*128;
    } else if (u < 1248){                            // dec M n-gate
        int u2 = u-1120; int ct = u2/8, kt = u2&7;
        const float* s = Mw + (size_t)(512 + ct*16 + r)*256 + kt*32 + q*8;
        #pragma unroll
        for (int e = 0; e < 8; ++e) v[e] = s[e];
        dst = fMn + (size_t)u2*128;
    } else {                                         // regW (out GEMM)
        int u2 = u-1248; int nt = u2/8, kt = u2&7;
        const float* s = regW + (size_t)(nt*16 + r)*256 + kt*32 + q*8;
        #pragma unroll
        for (int e = 0; e < 8; ++e) v[e] = s[e];
        dst = fRW + (size_t)u2*128;
    }
    s16x8 hi, lo;
    split8(v, hi, lo);
    dst[l] = hi;
    dst[64 + l] = lo;
}

// ---------------- main: per-block independent recurrence, zero inter-block sync ----
// Block owns rows [blk*16, blk*16+16), full H. Wave w owns h-cols [w*32,+32)
// (2 col-tiles x 3 gates each). h state: LDS double-buffered bf16 hi/lo planes.
// Weights streamed from L2 each step (pre-packed fragment order, coalesced).
// One __syncthreads per step.
extern "C" __global__ void __launch_bounds__(NTHR, 1)
gru_main(const float* __restrict__ x,
         const float* __restrict__ ebih, const float* __restrict__ ebhh,
         const float* __restrict__ dbhh, const float* __restrict__ cfold,
         const float* __restrict__ gi0,  const float* __restrict__ regb,
         const s16x8* __restrict__ fEWhh, const s16x8* __restrict__ fEWih,
         const s16x8* __restrict__ fRZc,  const s16x8* __restrict__ fRZp,
         const s16x8* __restrict__ fWn,   const s16x8* __restrict__ fMn,
         const s16x8* __restrict__ fRW,
         float* __restrict__ out)
{
    __shared__ unsigned short s_h[2][2][16][SH];   // [buf][hi/lo][row][col] 33.8KB

    const int tid  = threadIdx.x;
    const int w    = tid >> 6;
    const int lane = tid & 63;
    const int quad = lane >> 4;
    const int lcol = lane & 15;
    const int blk  = blockIdx.x;
    const int ct0  = w*2;
    const int row4 = quad*4;

    // zero h^0 (buf 0, both planes)
    for (int i = tid; i < 2*PLANE; i += NTHR) (&s_h[0][0][0][0])[i] = 0;

    // encoder biases per owned col
    float beR[2], beZ[2], beNi[2], beNh[2];
    #pragma unroll
    for (int c2 = 0; c2 < 2; ++c2){
        int c = (ct0+c2)*16 + lcol;
        beR[c2]  = ebih[c]     + ebhh[c];
        beZ[c2]  = ebih[256+c] + ebhh[256+c];
        beNi[c2] = ebih[512+c];
        beNh[c2] = ebhh[512+c];
    }
    __syncthreads();

    const float* xbase = x + (size_t)(blk*16 + lcol)*(256*64);
    f32x4 xv0, xv1, xv2, xv3;
    {   const float* p = xbase + quad*8;
        xv0 = *(const f32x4*)p;        xv1 = *(const f32x4*)(p+4);
        xv2 = *(const f32x4*)(p+32);   xv3 = *(const f32x4*)(p+36);
    }

    // stream-GEMM over one gate's K: 8 k-tiles x {AhBh, AhBl, AlBh}
    #define HMM(ACC, FB, U0) { \
        _Pragma("unroll") \
        for (int kt = 0; kt < 8; ++kt){ \
            s16x8 bh = (FB)[(size_t)((U0)+kt)*128 + lane]; \
            s16x8 bl = (FB)[(size_t)((U0)+kt)*128 + 64 + lane]; \
            ACC = MF(ah[kt], bh, ACC); ACC = MF(ah[kt], bl, ACC); ACC = MF(al[kt], bh, ACC); }}

    // =================== encoder ===================
    for (int g = 0; g < TSTEPS; ++g){
        const unsigned short* hb = &s_h[g&1][0][0][0];
        unsigned short*       ho = &s_h[(g+1)&1][0][0][0];

        // A-fragments of h^g (all waves read full K)
        s16x8 ah[8], al[8];
        #pragma unroll
        for (int kt = 0; kt < 8; ++kt){
            ah[kt] = *(const s16x8*)(hb +         lcol*SH + kt*32 + quad*8);
            al[kt] = *(const s16x8*)(hb + PLANE + lcol*SH + kt*32 + quad*8);
        }
        // x fragments
        s16x8 xah[2], xal[2];
        {   float xf[8];
            #pragma unroll
            for (int e = 0; e < 4; ++e){ xf[e] = xv0[e]; xf[4+e] = xv1[e]; }
            split8(xf, xah[0], xal[0]);
            #pragma unroll
            for (int e = 0; e < 4; ++e){ xf[e] = xv2[e]; xf[4+e] = xv3[e]; }
            split8(xf, xah[1], xal[1]);
        }
        // prefetch next step's x
        if (g+1 < TSTEPS){
            const float* p = xbase + (size_t)(g+1)*64 + quad*8;
            xv0 = *(const f32x4*)p;      xv1 = *(const f32x4*)(p+4);
            xv2 = *(const f32x4*)(p+32); xv3 = *(const f32x4*)(p+36);
        }

        #pragma unroll
        for (int c2 = 0; c2 < 2; ++c2){
            const int ct = ct0 + c2;
            f32x4 aR  = {beR[c2],beR[c2],beR[c2],beR[c2]};
            f32x4 aZ  = {beZ[c2],beZ[c2],beZ[c2],beZ[c2]};
            f32x4 aNi = {beNi[c2],beNi[c2],beNi[c2],beNi[c2]};
            f32x4 aNh = {beNh[c2],beNh[c2],beNh[c2],beNh[c2]};
            // x-GEMM (K=64): gates r,z,n-input
            #pragma unroll
            for (int kt = 0; kt < 2; ++kt){
                #pragma unroll
                for (int gg = 0; gg < 3; ++gg){
                    s16x8 bh = fEWih[(size_t)(ct*6 + gg*2 + kt)*128 + lane];
                    s16x8 bl = fEWih[(size_t)(ct*6 + gg*2 + kt)*128 + 64 + lane];
                    f32x4* A = (gg==0) ? &aR : (gg==1) ? &aZ : &aNi;
                    *A = MF(xah[kt], bh, *A); *A = MF(xah[kt], bl, *A); *A = MF(xal[kt], bh, *A);
                }
            }
            // h-GEMM (K=256)
            HMM(aR,  fEWhh, ct*24 + 0);
            HMM(aZ,  fEWhh, ct*24 + 8);
            HMM(aNh, fEWhh, ct*24 + 16);
            // elementwise + h write
            #pragma unroll
            for (int j = 0; j < 4; ++j){
                float r = sigmoidf_(aR[j]);
                float z = sigmoidf_(aZ[j]);
                float n = tanhf_(aNi[j] + r*aNh[j]);
                int rr = row4 + j, cc = ct*16 + lcol;
                float hold = bf16_to_f(hb[rr*SH + cc]) + bf16_to_f(hb[PLANE + rr*SH + cc]);
                float hv = (1.0f - z)*n + z*hold;
                unsigned short p1 = bf16_rne(hv);
                unsigned short p0 = bf16_rne(hv - bf16_to_f(p1));
                ho[rr*SH + cc] = p1;
                ho[PLANE + rr*SH + cc] = p0;
            }
        }
        __syncthreads();
    }

    // =================== decoder ===================
    float bcR[2], bcZ[2], bcNi[2], bcNh[2], bdR[2], bdZ[2];
    #pragma unroll
    for (int c2 = 0; c2 < 2; ++c2){
        int c = (ct0+c2)*16 + lcol;
        bdR[c2]  = dbhh[c];
        bdZ[c2]  = dbhh[256+c];
        bcR[c2]  = cfold[c]     + dbhh[c];
        bcZ[c2]  = cfold[256+c] + dbhh[256+c];
        bcNi[c2] = cfold[512+c];
        bcNh[c2] = dbhh[512+c];
    }
    const float bo = (w < 4) ? regb[w*16 + lcol] : 0.f;

    for (int g = TSTEPS; g <= 2*TSTEPS; ++g){
        const unsigned short* hb = &s_h[g&1][0][0][0];
        unsigned short*       ho = &s_h[(g+1)&1][0][0][0];

        s16x8 ah[8], al[8];
        #pragma unroll
        for (int kt = 0; kt < 8; ++kt){
            ah[kt] = *(const s16x8*)(hb +         lcol*SH + kt*32 + quad*8);
            al[kt] = *(const s16x8*)(hb + PLANE + lcol*SH + kt*32 + quad*8);
        }

        if (g < 2*TSTEPS){
            const bool first = (g == TSTEPS);
            const s16x8* rz = first ? fRZp : fRZc;
            #pragma unroll
            for (int c2 = 0; c2 < 2; ++c2){
                const int ct = ct0 + c2;
                f32x4 aR, aZ, aNi, aNh;
                aNh = (f32x4){bcNh[c2],bcNh[c2],bcNh[c2],bcNh[c2]};
                if (first){
                    #pragma unroll
                    for (int j = 0; j < 4; ++j){
                        const float* gp = gi0 + (size_t)(blk*16 + row4 + j)*G3 + ct*16 + lcol;
                        aR[j]  = gp[0]   + bdR[c2];
                        aZ[j]  = gp[256] + bdZ[c2];
                        aNi[j] = gp[512];
                    }
                } else {
                    aR  = (f32x4){bcR[c2],bcR[c2],bcR[c2],bcR[c2]};
                    aZ  = (f32x4){bcZ[c2],bcZ[c2],bcZ[c2],bcZ[c2]};
                    aNi = (f32x4){bcNi[c2],bcNi[c2],bcNi[c2],bcNi[c2]};
                }
                HMM(aR,  rz,  ct*16 + 0);
                HMM(aZ,  rz,  ct*16 + 8);
                HMM(aNh, fWn, ct*8);
                if (!first) HMM(aNi, fMn, ct*8);
                #pragma unroll
                for (int j = 0; j < 4; ++j){
                    float r = sigmoidf_(aR[j]);
                    float z = sigmoidf_(aZ[j]);
                    float n = tanhf_(aNi[j] + r*aNh[j]);
                    int rr = row4 + j, cc = ct*16 + lcol;
                    float hold = bf16_to_f(hb[rr*SH + cc]) + bf16_to_f(hb[PLANE + rr*SH + cc]);
                    float hv = (1.0f - z)*n + z*hold;
                    unsigned short p1 = bf16_rne(hv);
                    unsigned short p0 = bf16_rne(hv - bf16_to_f(p1));
                    ho[rr*SH + cc] = p1;
                    ho[PLANE + rr*SH + cc] = p0;
                }
            }
        }
        // out_{g-TSTEPS-1} = h^g @ regW^T + regb  (uses this step's A-frags)
        if (g > TSTEPS && w < 4){
            f32x4 oa = {bo, bo, bo, bo};
            HMM(oa, fRW, w*8);
            const int i = g - TSTEPS - 1;
            #pragma unroll
            for (int j = 0; j < 4; ++j)
                out[(size_t)(blk*16 + row4 + j)*(TSTEPS*Fsz) + (size_t)i*Fsz + w*16 + lcol] = oa[j];
        }
        __syncthreads();
    }
    #undef HMM
}

extern "C" void kernel_launch(void* const* d_in, const int* in_sizes, int n_in,
                              void* d_out, int out_size, void* d_ws, size_t ws_size,
                              hipStream_t stream)
{
    (void)in_sizes; (void)n_in; (void)out_size; (void)ws_size;
    const float* x    = (const float*)d_in[0];
    const float* eWih = (const float*)d_in[1];
    const float* eWhh = (const float*)d_in[2];
    const float* ebih = (const float*)d_in[3];
    const float* ebhh = (const float*)d_in[4];
    const float* dWih = (const float*)d_in[5];
    const float* dWhh = (const float*)d_in[6];
    const float* dbih = (const float*)d_in[7];
    const float* dbhh = (const float*)d_in[8];
    const float* regW = (const float*)d_in[9];
    const float* regb = (const float*)d_in[10];
    float* out = (float*)d_out;

    float* Mw    = (float*)d_ws;                 // 768*256
    float* gi0   = Mw + G3*Hsz;                  // 512*768
    float* cfold = gi0 + (size_t)Bsz*G3;         // 768 (+pad to 1024)
    s16x8* fEWhh = (s16x8*)(cfold + 1024);       // 384*128 frag entries
    s16x8* fEWih = fEWhh + (size_t)384*128;      // 96*128
    s16x8* fRZc  = fEWih + (size_t)96*128;       // 256*128
    s16x8* fRZp  = fRZc  + (size_t)256*128;      // 256*128
    s16x8* fWn   = fRZp  + (size_t)256*128;      // 128*128
    s16x8* fMn   = fWn   + (size_t)128*128;      // 128*128
    s16x8* fRW   = fMn   + (size_t)128*128;      // 32*128

    hipLaunchKernelGGL(gru_setup, dim3(2307), dim3(256), 0, stream,
                       x, dWih, dbih, regW, regb, Mw, cfold, gi0);
    hipLaunchKernelGGL(gru_pack, dim3(1280), dim3(64), 0, stream,
                       eWhh, eWih, dWhh, Mw, regW,
                       fEWhh, fEWih, fRZc, fRZp, fWn, fMn, fRW);
    hipLaunchKernelGGL(gru_main, dim3(NBLK), dim3(NTHR), 0, stream,
                       x, ebih, ebhh, dbhh, cfold, gi0, regb,
                       fEWhh, fEWih, fRZc, fRZp, fWn, fMn, fRW, out);
}

// Round 6
// 1099.001 us; speedup vs baseline: 4.5345x; 4.5345x over previous
//
#include <hip/hip_runtime.h>
#include <math.h>

#define Bsz 512
#define Fsz 64
#define Hsz 256
#define TSTEPS 128
#define G3 768

#define BG 16            // batch groups (32 rows each)
#define HB 16            // hidden-slice blocks (16 cols x 3 gates each)
#define NBLK 256
#define NTHR 256
#define PL (Bsz*Hsz)     // u16 plane stride (131072)

// LDS: DOUBLE-buffered K-reduction scratch -> single barrier per step.
// per buffer: 32 gate slots + 8 oa slots; slot = 64 lanes x f32x4
#define RED_SLOTS 40
#define OFF_B (2*RED_SLOTS*64*16)      // 81920
#define SMEM_BYTES (OFF_B + 512)

typedef float f32x4 __attribute__((ext_vector_type(4)));
typedef short s16x8 __attribute__((ext_vector_type(8)));

#define MF(a,b,c) __builtin_amdgcn_mfma_f32_16x16x32_bf16(a,b,c,0,0,0)

static __device__ __forceinline__ unsigned short bf16_rne(float f){
    union { float f; unsigned u; } v; v.f = f;
    return (unsigned short)((v.u + 0x7FFFu + ((v.u >> 16) & 1u)) >> 16);
}
static __device__ __forceinline__ float bf16_to_f(unsigned short h){
    union { unsigned u; float f; } v; v.u = ((unsigned)h) << 16; return v.f;
}
static __device__ __forceinline__ void split8(const float* p, s16x8& hi, s16x8& lo){
    #pragma unroll
    for (int t = 0; t < 8; ++t){
        float f = p[t];
        unsigned short h = bf16_rne(f);
        hi[t] = (short)h;
        lo[t] = (short)bf16_rne(f - bf16_to_f(h));
    }
}
// fast transcendentals (verified R4: absmax unchanged)
static __device__ __forceinline__ float sigmoidf_(float v){
    return __builtin_amdgcn_rcpf(1.0f + __builtin_amdgcn_exp2f(-1.44269504f*v));
}
static __device__ __forceinline__ float tanhf_(float v){
    return 1.0f - 2.0f*__builtin_amdgcn_rcpf(1.0f + __builtin_amdgcn_exp2f(2.88539008f*v));
}

// ---- MALL-coherent (cache-bypass) ops: sc0 sc1 = system scope ----
__device__ __forceinline__ s16x8 load_sys_frag(const unsigned short* p){
    s16x8 r;
    asm volatile("global_load_dwordx4 %0, %1, off sc0 sc1" : "=v"(r) : "v"(p) : "memory");
    return r;
}
__device__ __forceinline__ unsigned load_sys_u16(const unsigned short* p){
    unsigned r;
    asm volatile("global_load_ushort %0, %1, off sc0 sc1" : "=v"(r) : "v"(p) : "memory");
    return r;
}
__device__ __forceinline__ void store_sys_b16(unsigned short* p, unsigned v){
    asm volatile("global_store_short %0, %1, off sc0 sc1" :: "v"(p), "v"(v) : "memory");
}
__device__ __forceinline__ void store_sys_b32u(unsigned* p, unsigned v){
    asm volatile("global_store_dword %0, %1, off sc0 sc1" :: "v"(p), "v"(v) : "memory");
}
__device__ __forceinline__ int load_flag(const int* p){
    int r;
    asm volatile("global_load_dword %0, %1, off sc0 sc1\n\ts_waitcnt vmcnt(0)"
                 : "=v"(r) : "v"(p) : "memory");
    return r;
}
__device__ __forceinline__ void waitcnt0(){ asm volatile("s_waitcnt vmcnt(0)" ::: "memory"); }
// register barriers: pin uses of asm-load results after a preceding waitcnt
__device__ __forceinline__ void regbarh(s16x8& v){ asm volatile("" : "+v"(v)); }
__device__ __forceinline__ void regbar32(unsigned& v){ asm volatile("" : "+v"(v)); }

// ---------------- setup: M = dec_Wih@reg_W, cfold = dec_Wih@reg_b + dec_bih,
// ---------------- gi0 = x[:,127,:]@dec_Wih.T + dec_bih
extern "C" __global__ void gru_setup(const float* __restrict__ x,
                                     const float* __restrict__ dWih,
                                     const float* __restrict__ dbih,
                                     const float* __restrict__ regW,
                                     const float* __restrict__ regb,
                                     float* __restrict__ Mw,
                                     float* __restrict__ cfold,
                                     float* __restrict__ gi0)
{
    int idx = blockIdx.x*blockDim.x + threadIdx.x;
    if (idx < G3*Hsz) {
        int g = idx >> 8, j = idx & 255;
        float a = 0.f;
        #pragma unroll 8
        for (int f = 0; f < Fsz; ++f) a += dWih[g*Fsz + f]*regW[f*Hsz + j];
        Mw[idx] = a;
    } else if (idx < G3*Hsz + G3) {
        int g = idx - G3*Hsz;
        float a = dbih[g];
        #pragma unroll 8
        for (int f = 0; f < Fsz; ++f) a += dWih[g*Fsz + f]*regb[f];
        cfold[g] = a;
    } else {
        int e = idx - (G3*Hsz + G3);
        if (e < Bsz*G3) {
            int b = e / G3, g = e - b*G3;
            const float* xp = x + (size_t)b*(256*64) + 127*64;
            float a = dbih[g];
            #pragma unroll 8
            for (int f = 0; f < Fsz; ++f) a += xp[f]*dWih[g*Fsz + f];
            gi0[e] = a;
        }
    }
}

// ---------------- persistent GRU: hi/lo planes + 1-bit tag-in-LSB ----------------
// hbuf: 2 slots x {hi plane, lo plane} of [512][256] u16. Every stored u16 has
// LSB = tagbit(gen) = (gen>>1)&1; producer clears the LSB and computes lo to
// compensate hi's (tagged) rounding -> pair precision ~2^-15 rel.
// Producer: EW -> tagged u16 stores (both planes) -> flag=g+1 (no ack).
// Consumer: gate on 16 relevant flags -> load frags ONCE -> tag-validate both
// planes -> miss-only reload. Ring-2 slot safety: writes of gen g+2 require all
// blocks validated gen g+1, which implies their reads of gen g completed.
extern "C" __global__ void __launch_bounds__(NTHR, 1)
gru_persistent(const float* __restrict__ x,
               const float* __restrict__ eWih, const float* __restrict__ eWhh,
               const float* __restrict__ ebih, const float* __restrict__ ebhh,
               const float* __restrict__ dWhh, const float* __restrict__ dbhh,
               const float* __restrict__ Mw,   const float* __restrict__ cfold,
               const float* __restrict__ gi0,  const float* __restrict__ regW,
               const float* __restrict__ regb,
               unsigned short* __restrict__ hbuf, unsigned* __restrict__ canary,
               float* __restrict__ out)
{
    extern __shared__ char lds[];
    f32x4* s_redv = (f32x4*)lds;
    float* s_bias = (float*)(lds + OFF_B);
    float* s_dbh  = s_bias + 64;
    float* s_b3   = s_bias + 112;

    const int tid  = threadIdx.x;
    const int wv   = tid >> 6;
    const int lane = tid & 63;
    const int quad = lane >> 4;
    const int lcol = lane & 15;
    const int bg   = blockIdx.x & 15;
    const int hb   = blockIdx.x >> 4;
    const int hcol = hb*16 + lcol;
    const int mw   = wv & 1;
    const int kh   = wv >> 1;
    const int jb   = kh*2;
    const int hr0  = mw*16 + quad*4 + jb;
    const f32x4 z4 = {0.f, 0.f, 0.f, 0.f};

    unsigned* mycan = canary + ((size_t)bg*64 + hb*4 + wv)*4;
    const int fidx  = wv*16 + (lane & 15);
    const int* fp   = (const int*)canary + ((size_t)bg*64 + fidx)*4;
    const int fmine = ((fidx >> 2) == hb);

    // ---- encoder weight fragments ----
    s16x8 wfh[3][2], wfl[3][2];
    s16x8 ufh[3], ufl[3];
    s16x8 rwh[2], rwl[2];
    #pragma unroll
    for (int g = 0; g < 3; ++g){
        #pragma unroll
        for (int q = 0; q < 2; ++q)
            split8(eWhh + (size_t)(g*256 + hcol)*256 + wv*64 + q*32 + quad*8,
                   wfh[g][q], wfl[g][q]);
        split8(eWih + (size_t)(g*256 + hcol)*64 + kh*32 + quad*8, ufh[g], ufl[g]);
    }
    if (tid < 16){
        int c = hb*16 + tid;
        s_bias[tid]    = ebih[c]       + ebhh[c];
        s_bias[16+tid] = ebih[256+c]   + ebhh[256+c];
        s_bias[32+tid] = ebih[512+c];
        s_bias[48+tid] = ebhh[512+c];
    }
    __syncthreads();

    for (int g = 0; g <= 2*TSTEPS; ++g){
        const bool enc  = (g < TSTEPS);
        const bool last = (g == 2*TSTEPS);
        const int  p    = g & 1;
        const unsigned tb    = (unsigned)((g >> 1) & 1);
        const unsigned otagb = (unsigned)(((g+1) >> 1) & 1);
        const unsigned short* hinH = hbuf + (size_t)(g & 1)*2*PL;
        const unsigned short* hinL = hinH + PL;
        unsigned short* houtH = hbuf + (size_t)((g+1) & 1)*2*PL;
        unsigned short* houtL = houtH + PL;

        // ---- enc->dec transition ----
        if (g == TSTEPS){
            #pragma unroll
            for (int gg = 0; gg < 3; ++gg)
                #pragma unroll
                for (int q = 0; q < 2; ++q)
                    split8(dWhh + (size_t)(gg*256 + hcol)*256 + wv*64 + q*32 + quad*8,
                           wfh[gg][q], wfl[gg][q]);
            #pragma unroll
            for (int q = 0; q < 2; ++q){
                split8(Mw   + (size_t)(2*256 + hcol)*256 + wv*64 + q*32 + quad*8,
                       ufh[q], ufl[q]);
                split8(regW + (size_t)(hb*4 + (lcol & 3))*256 + wv*64 + q*32 + quad*8,
                       rwh[q], rwl[q]);
            }
            if (tid < 16){
                int c = hb*16 + tid;
                s_bias[tid]    = cfold[c]     + dbhh[c];
                s_bias[16+tid] = cfold[256+c] + dbhh[256+c];
                s_bias[32+tid] = cfold[512+c];
                s_dbh[tid]     = dbhh[c];
                s_dbh[16+tid]  = dbhh[256+c];
                s_dbh[32+tid]  = dbhh[512+c];
            }
            if (tid < 4) s_b3[tid] = regb[hb*4 + tid];
            __syncthreads();
        }
        if (g == TSTEPS + 1){
            #pragma unroll
            for (int gg = 0; gg < 2; ++gg)
                #pragma unroll
                for (int q = 0; q < 2; ++q){
                    float tmp[8];
                    const float* pa = dWhh + (size_t)(gg*256 + hcol)*256 + wv*64 + q*32 + quad*8;
                    const float* pb = Mw   + (size_t)(gg*256 + hcol)*256 + wv*64 + q*32 + quad*8;
                    #pragma unroll
                    for (int t2 = 0; t2 < 8; ++t2) tmp[t2] = pa[t2] + pb[t2];
                    split8(tmp, wfh[gg][q], wfl[gg][q]);
                }
        }

        // ---- accumulator init ----
        f32x4 aR[2], aZ[2], aNi[2], aNh[2], oa[2];
        oa[0] = z4; oa[1] = z4;
        if (wv == 0 && !last){
            if (g == TSTEPS){
                #pragma unroll
                for (int m = 0; m < 2; ++m)
                    #pragma unroll
                    for (int j = 0; j < 4; ++j){
                        int grow_ = bg*32 + m*16 + quad*4 + j;
                        const float* gp = gi0 + (size_t)grow_*G3 + hcol;
                        aR[m][j]  = gp[0]   + s_dbh[lcol];
                        aZ[m][j]  = gp[256] + s_dbh[16+lcol];
                        aNi[m][j] = gp[512];
                        aNh[m][j] = s_dbh[32+lcol];
                    }
            } else {
                float bR = s_bias[lcol], bZ = s_bias[16+lcol], bNi = s_bias[32+lcol];
                float bNh = enc ? s_bias[48+lcol] : s_dbh[32+lcol];
                #pragma unroll
                for (int m = 0; m < 2; ++m){
                    aR[m] = (f32x4){bR,bR,bR,bR}; aZ[m] = (f32x4){bZ,bZ,bZ,bZ};
                    aNi[m] = (f32x4){bNi,bNi,bNi,bNi}; aNh[m] = (f32x4){bNh,bNh,bNh,bNh};
                }
            }
        } else {
            #pragma unroll
            for (int m = 0; m < 2; ++m){ aR[m]=z4; aZ[m]=z4; aNi[m]=z4; aNh[m]=z4; }
        }

        // ---- x work fully BEFORE the gate (off critical path) ----
        if (enc){
            const float* xp = x + (size_t)(bg*32 + mw*16 + lcol)*(256*64)
                                + (size_t)g*64 + kh*32 + quad*8;
            f32x4 xv0 = *(const f32x4*)xp;
            f32x4 xv1 = *(const f32x4*)(xp + 4);
            float xf[8];
            #pragma unroll
            for (int e = 0; e < 4; ++e){ xf[e] = xv0[e]; xf[4+e] = xv1[e]; }
            s16x8 xh, xl;
            split8(xf, xh, xl);
            #define XMF(M) { \
                aR[M] =MF(xh,ufh[0],aR[M]);  aR[M] =MF(xh,ufl[0],aR[M]);  aR[M] =MF(xl,ufh[0],aR[M]);  \
                aZ[M] =MF(xh,ufh[1],aZ[M]);  aZ[M] =MF(xh,ufl[1],aZ[M]);  aZ[M] =MF(xl,ufh[1],aZ[M]);  \
                aNi[M]=MF(xh,ufh[2],aNi[M]); aNi[M]=MF(xh,ufl[2],aNi[M]); aNi[M]=MF(xl,ufh[2],aNi[M]); }
            if (mw == 0) XMF(0) else XMF(1)
            #undef XMF
        }

        // ---- gate: sleepless poll of the 16 relevant producer flags ----
        if (g){
            while (1){
                int v = load_flag(fp);
                if (__all(fmine | (v >= g))) break;
            }
        }

        // ---- load A-fragments + old-h ONCE, then tag-validate ----
        const size_t fb = (size_t)(bg*32 + lcol)*256 + wv*64 + quad*8;
        const unsigned short* hoHp = hinH + (size_t)(bg*32 + hr0)*256 + hcol;
        const unsigned short* hoLp = hinL + (size_t)(bg*32 + hr0)*256 + hcol;
        s16x8 th[4], tl[4];
        #pragma unroll
        for (int fi = 0; fi < 4; ++fi){
            const int m = fi >> 1, q = fi & 1;
            th[fi] = load_sys_frag(hinH + fb + m*4096 + q*32);
            tl[fi] = load_sys_frag(hinL + fb + m*4096 + q*32);
        }
        unsigned hh0 = load_sys_u16(hoHp), hh1 = load_sys_u16(hoHp + 256);
        unsigned hl0 = load_sys_u16(hoLp), hl1 = load_sys_u16(hoLp + 256);

        {
            const unsigned tt = tb * 0x00010001u;
            unsigned done = 0;
            #define UPD() { \
                _Pragma("unroll") \
                for (int fi = 0; fi < 4; ++fi){ \
                    if (!((done >> fi) & 1u)){ const unsigned* c = (const unsigned*)&th[fi]; \
                        if ((((c[0]^tt)|(c[1]^tt)|(c[2]^tt)|(c[3]^tt)) & 0x00010001u) == 0u) done |= (1u<<fi); } \
                    if (!((done >> (4+fi)) & 1u)){ const unsigned* c = (const unsigned*)&tl[fi]; \
                        if ((((c[0]^tt)|(c[1]^tt)|(c[2]^tt)|(c[3]^tt)) & 0x00010001u) == 0u) done |= (1u<<(4+fi)); } } \
                if (!((done>>8)&1u)  && (((hh0^tb)&1u)==0u)) done |= 0x100u; \
                if (!((done>>9)&1u)  && (((hh1^tb)&1u)==0u)) done |= 0x200u; \
                if (!((done>>10)&1u) && (((hl0^tb)&1u)==0u)) done |= 0x400u; \
                if (!((done>>11)&1u) && (((hl1^tb)&1u)==0u)) done |= 0x800u; }

            waitcnt0();
            #pragma unroll
            for (int fi = 0; fi < 4; ++fi){ regbarh(th[fi]); regbarh(tl[fi]); }
            regbar32(hh0); regbar32(hh1); regbar32(hl0); regbar32(hl1);
            UPD();
            while (!__all((int)(done == 0xFFFu))){
                #pragma unroll
                for (int fi = 0; fi < 4; ++fi){
                    const int m = fi >> 1, q = fi & 1;
                    if (!((done >> fi) & 1u))     th[fi] = load_sys_frag(hinH + fb + m*4096 + q*32);
                    if (!((done >> (4+fi)) & 1u)) tl[fi] = load_sys_frag(hinL + fb + m*4096 + q*32);
                }
                if (!((done>>8)&1u))  hh0 = load_sys_u16(hoHp);
                if (!((done>>9)&1u))  hh1 = load_sys_u16(hoHp + 256);
                if (!((done>>10)&1u)) hl0 = load_sys_u16(hoLp);
                if (!((done>>11)&1u)) hl1 = load_sys_u16(hoLp + 256);
                waitcnt0();
                #pragma unroll
                for (int fi = 0; fi < 4; ++fi){ regbarh(th[fi]); regbarh(tl[fi]); }
                regbar32(hh0); regbar32(hh1); regbar32(hl0); regbar32(hl1);
                UPD();
            }
            #undef UPD
        }

        // ---- h-GEMMs: fragments consumed DIRECTLY (no unpack) ----
        #pragma unroll
        for (int m = 0; m < 2; ++m){
            #pragma unroll
            for (int q = 0; q < 2; ++q){
                const s16x8 ah = th[m*2+q];
                const s16x8 al = tl[m*2+q];
                if (!last){
                    aR[m]=MF(ah,wfh[0][q],aR[m]); aR[m]=MF(ah,wfl[0][q],aR[m]); aR[m]=MF(al,wfh[0][q],aR[m]);
                    aZ[m]=MF(ah,wfh[1][q],aZ[m]); aZ[m]=MF(ah,wfl[1][q],aZ[m]); aZ[m]=MF(al,wfh[1][q],aZ[m]);
                    aNh[m]=MF(ah,wfh[2][q],aNh[m]); aNh[m]=MF(ah,wfl[2][q],aNh[m]); aNh[m]=MF(al,wfh[2][q],aNh[m]);
                    if (!enc && g > TSTEPS){
                        aNi[m]=MF(ah,ufh[q],aNi[m]); aNi[m]=MF(ah,ufl[q],aNi[m]); aNi[m]=MF(al,ufh[q],aNi[m]);
                    }
                }
                if (g >= TSTEPS + 1){
                    oa[m]=MF(ah,rwh[q],oa[m]); oa[m]=MF(ah,rwl[q],oa[m]); oa[m]=MF(al,rwh[q],oa[m]);
                }
            }
        }

        // ---- K-reduction partials into buffer p; ONE barrier per step ----
        if (!last){
            f32x4* rp = s_redv + ((size_t)p*RED_SLOTS + wv*8)*64 + lane;
            rp[0]   = aR[0]; rp[64]  = aZ[0]; rp[128] = aNi[0]; rp[192] = aNh[0];
            rp[256] = aR[1]; rp[320] = aZ[1]; rp[384] = aNi[1]; rp[448] = aNh[1];
        }
        if (g >= TSTEPS + 1){
            f32x4* op = s_redv + ((size_t)p*RED_SLOTS + 32 + wv*2)*64 + lane;
            op[0] = oa[0]; op[64] = oa[1];
        }
        __syncthreads();

        // ---- elementwise + tagged u16 stores (both planes) + flag ----
        if (!last){
            f32x4 R = z4, Z = z4, Ni = z4, Nh = z4;
            #pragma unroll
            for (int w2 = 0; w2 < 4; ++w2){
                const f32x4* rp = s_redv + ((size_t)p*RED_SLOTS + w2*8 + mw*4)*64 + lane;
                R += rp[0]; Z += rp[64]; Ni += rp[128]; Nh += rp[192];
            }
            #define EW(J, HH, HL, RO) { \
                float r = sigmoidf_(R[J]); \
                float z = sigmoidf_(Z[J]); \
                float n = tanhf_(Ni[J] + r*Nh[J]); \
                float hold = bf16_to_f((unsigned short)(HH)) + bf16_to_f((unsigned short)(HL)); \
                float hv = (1.0f - z)*n + z*hold; \
                unsigned short p1 = (unsigned short)((bf16_rne(hv) & 0xFFFEu) | otagb); \
                unsigned short p0 = (unsigned short)((bf16_rne(hv - bf16_to_f(p1)) & 0xFFFEu) | otagb); \
                store_sys_b16(houtH + (size_t)(bg*32 + hr0 + RO)*256 + hcol, (unsigned)p1); \
                store_sys_b16(houtL + (size_t)(bg*32 + hr0 + RO)*256 + hcol, (unsigned)p0); }
            if (jb == 0){ EW(0, hh0, hl0, 0); EW(1, hh1, hl1, 1); }
            else        { EW(2, hh0, hl0, 0); EW(3, hh1, hl1, 1); }
            #undef EW
            if (lane == 0) store_sys_b32u(mycan, (unsigned)(g + 1));
        }

        // ---- out_{g-129} = H @ regW^T + regb ----
        if (g >= TSTEPS + 1 && wv >= 2){
            const int m2 = wv - 2;
            float b3 = s_b3[lcol & 3];
            f32x4 ot = {b3, b3, b3, b3};
            #pragma unroll
            for (int w2 = 0; w2 < 4; ++w2)
                ot += s_redv[((size_t)p*RED_SLOTS + 32 + w2*2 + m2)*64 + lane];
            if (lcol < 4){
                const int oidx = g - TSTEPS - 1;
                #pragma unroll
                for (int j = 0; j < 4; ++j)
                    out[(size_t)(bg*32 + m2*16 + quad*4 + j)*(TSTEPS*Fsz)
                        + (size_t)oidx*Fsz + hb*4 + lcol] = ot[j];
            }
        }
    }
}

extern "C" void kernel_launch(void* const* d_in, const int* in_sizes, int n_in,
                              void* d_out, int out_size, void* d_ws, size_t ws_size,
                              hipStream_t stream)
{
    (void)in_sizes; (void)n_in; (void)out_size; (void)ws_size;
    const float* x    = (const float*)d_in[0];
    const float* eWih = (const float*)d_in[1];
    const float* eWhh = (const float*)d_in[2];
    const float* ebih = (const float*)d_in[3];
    const float* ebhh = (const float*)d_in[4];
    const float* dWih = (const float*)d_in[5];
    const float* dWhh = (const float*)d_in[6];
    const float* dbih = (const float*)d_in[7];
    const float* dbhh = (const float*)d_in[8];
    const float* regW = (const float*)d_in[9];
    const float* regb = (const float*)d_in[10];
    float* out = (float*)d_out;

    unsigned short* hbuf = (unsigned short*)d_ws;        // 2 slots x 2 planes x 512x256 u16 (1MB)
    float* Mw    = (float*)d_ws + 2*Bsz*Hsz;             // 768*256
    float* gi0   = Mw + G3*Hsz;                          // 512*768
    float* cfold = gi0 + (size_t)Bsz*G3;                 // 768 (+pad)
    unsigned* canary = (unsigned*)(cfold + 1024);        // 16 bg x 64 wave-flags, 16B stride

    // slot0 (h^0=0): zeros -> LSB tag 0 == tag(gen0). slot1: 0x03 bytes -> LSB 1 != tag(gen1)=0.
    hipMemsetAsync(hbuf, 0, (size_t)2*PL*sizeof(unsigned short), stream);
    hipMemsetAsync(hbuf + (size_t)2*PL, 3, (size_t)2*PL*sizeof(unsigned short), stream);
    hipMemsetAsync(canary, 0, (size_t)BG*64*4*sizeof(unsigned), stream);

    hipLaunchKernelGGL(gru_setup, dim3(2307), dim3(256), 0, stream,
                       x, dWih, dbih, regW, regb, Mw, cfold, gi0);

    hipFuncSetAttribute((const void*)gru_persistent,
                        hipFuncAttributeMaxDynamicSharedMemorySize, SMEM_BYTES);

    void* args[] = { (void*)&x, (void*)&eWih, (void*)&eWhh, (void*)&ebih, (void*)&ebhh,
                     (void*)&dWhh, (void*)&dbhh, (void*)&Mw, (void*)&cfold, (void*)&gi0,
                     (void*)&regW, (void*)&regb, (void*)&hbuf, (void*)&canary, (void*)&out };
    hipError_t rc = hipLaunchCooperativeKernel((const void*)gru_persistent,
                                               dim3(NBLK), dim3(NTHR), args,
                                               SMEM_BYTES, stream);
    if (rc != hipSuccess) {
        hipLaunchKernelGGL(gru_persistent, dim3(NBLK), dim3(NTHR), SMEM_BYTES, stream,
                           x, eWih, eWhh, ebih, ebhh, dWhh, dbhh, Mw, cfold, gi0,
                           regW, regb, hbuf, canary, out);
    }
}